// Round 2
// baseline (279.115 us; speedup 1.0000x reference)
//
#include <hip/hip_runtime.h>
#include <hip/hip_bf16.h>

typedef __bf16 bf16x8 __attribute__((ext_vector_type(8)));
typedef __bf16 bf16x4 __attribute__((ext_vector_type(4)));
typedef float floatx4 __attribute__((ext_vector_type(4)));

// Async global->LDS DMA, 16 B per lane. Dest is wave-uniform base + lane*16.
__device__ __forceinline__ void async16(void* lds, const void* g) {
  __builtin_amdgcn_global_load_lds(
      (const __attribute__((address_space(1))) unsigned int*)g,
      (__attribute__((address_space(3))) unsigned int*)lds, 16, 0, 0);
}

// Fused preprocess: x->bf16 (blocks 0..2047), K->bf16 (2048..3071),
// V->Vt bf16 transpose (3072..4095), lsum zero (block 4096).
__global__ __launch_bounds__(256) void preprocess_kernel(
    const float* __restrict__ x, const float* __restrict__ Kp,
    const float* __restrict__ V, __bf16* __restrict__ xb,
    __bf16* __restrict__ Kb, __bf16* __restrict__ Vt,
    float* __restrict__ lsum) {
  const int b = blockIdx.x;
  const int t = threadIdx.x;
  if (b < 2048) {
#pragma unroll
    for (int k = 0; k < 4; ++k) {
      const int i = b * 1024 + k * 256 + t;
      float4 v = ((const float4*)x)[i];
      bf16x4 o = {(__bf16)v.x, (__bf16)v.y, (__bf16)v.z, (__bf16)v.w};
      ((bf16x4*)xb)[i] = o;
    }
  } else if (b < 3072) {
#pragma unroll
    for (int k = 0; k < 4; ++k) {
      const int i = (b - 2048) * 1024 + k * 256 + t;
      float4 v = ((const float4*)Kp)[i];
      bf16x4 o = {(__bf16)v.x, (__bf16)v.y, (__bf16)v.z, (__bf16)v.w};
      ((bf16x4*)Kb)[i] = o;
    }
  } else if (b < 4096) {
    __shared__ float tile[64][65];
    const int bb = b - 3072;
    const int bx = bb & 63, by = bb >> 6;
    for (int i = t; i < 64 * 64; i += 256) {
      const int r = i >> 6, c = i & 63;
      tile[r][c] = V[(size_t)(bx * 64 + r) * 1024 + by * 64 + c];
    }
    __syncthreads();
    for (int i = t; i < 64 * 64; i += 256) {
      const int r = i >> 6, c = i & 63;
      Vt[(size_t)(by * 64 + r) * 4096 + bx * 64 + c] = (__bf16)tile[c][r];
    }
  } else {
#pragma unroll
    for (int k = 0; k < 8; ++k)
      ((floatx4*)lsum)[k * 256 + t] = floatx4{0.f, 0.f, 0.f, 0.f};
  }
}

// C = A (MxK bf16, k-contig) x B (N rows of K bf16, k-contig).
// BM=256, BN=128, BK=64. 512 threads = 8 waves, wave-tile 64x64 (4x4 frags).
// Deep-pipelined schedule (T3+T4+T5 on top of the proven T2 swizzle):
//  - LDS triple buffer: 3 x (A 32KB + B 16KB) = 144 KiB; tile T in buf T%3.
//  - 2 phases per K-tile, each: {ds_read subtile || stage 3 slabs of tile T+2
//    via global_load_lds} -> s_barrier -> lgkmcnt(0) -> setprio(1) 16 MFMA
//    setprio(0) -> s_barrier. Counted s_waitcnt vmcnt(6) once per K-tile
//    (waits tile T+1 only; T+2's 6 loads stay in flight across barriers).
//    Never vmcnt(0) except the tail. Raw s_barrier (no __syncthreads drain).
//  - slab = 64 rows x 64 k = 8 KB = 512 lanes x 16 B (one global_load_lds
//    per thread). A: 4 slabs/tile, B: 2 slabs/tile.
// Swizzle (proven, SQ_LDS_BANK_CONFLICT=0): 16-B unit (row m, chunk q) at
// unit 8m + (q^(m&7)); LDS dest linear (t*16), global source pre-swizzled
// (thread t: row t>>3, chunk (t&7)^((t>>3)&7)). k-slice 1 addr = ks0 ^ 64.
// Safety audit: buffer b's ds_reads drain (lgkm0 + closing barrier) a full
// K-tile before any stage re-targets b; vmcnt counts are exact because
// global_load_lds ops are the only VMEM in the loop.
// MODE 0: P = exp(min(dot/32,30)) -> bf16 Cb + fused row-sum atomicAdd.
// MODE 1: out = dot / lsum[m] -> fp32 Cf.
template <int MODE, int KS, int NS>
__global__ __launch_bounds__(512, 2) void gemm_kernel(const __bf16* __restrict__ A,
                                                      const __bf16* __restrict__ B,
                                                      __bf16* __restrict__ Cb,
                                                      float* __restrict__ Cf,
                                                      float* __restrict__ lsum) {
  constexpr int BK = 64;
  constexpr int NT = KS / BK;
  constexpr int NNT = NS / 128;
  __shared__ char lds[147456];  // 3 x 49152 (A 32K + B 16K per buffer)

  const int t = threadIdx.x;
  const int lane = t & 63;
  const int w = t >> 6;
  const int wr = w >> 1;  // 0..3  (A 64-row band)
  const int wc = w & 1;   // 0..1  (B 64-row band)

  const int id = blockIdx.x;
  const int g = id & 7;
  const int s = id >> 3;
  const int mt = g * 4 + s / NNT;
  const int nt = s % NNT;
  const int m0 = mt * 256;
  const int n0 = nt * 128;

  // staging: thread t -> row t>>3 of each 64-row slab, chunk (t&7)^((t>>3)&7),
  // LDS dest = slab base + t*16 (linear).
  const int rowT = t >> 3;
  const int cg = (t & 7) ^ (rowT & 7);
  const __bf16* aS = A + (size_t)(m0 + rowT) * KS + cg * 8;
  const __bf16* bS = B + (size_t)(n0 + rowT) * KS + cg * 8;
  const int dT = t * 16;

  // fragment read offsets
  const int rl = lane & 15;
  const int qq = lane >> 4;
  const int fo = rl * 128 + ((qq ^ (rl & 7)) << 4);
  const int aBase = wr * 8192 + fo;          // + i*2048; ks1: ^64
  const int bBase = 32768 + wc * 8192 + fo;  // + j*2048; ks1: ^64

  floatx4 acc[4][4] = {};

  // prologue: stage tile 0 -> buf0, tile 1 -> buf1 (6 loads each, in order)
#pragma unroll
  for (int s2 = 0; s2 < 4; ++s2)
    async16(lds + s2 * 8192 + dT, aS + (size_t)s2 * 64 * KS);
#pragma unroll
  for (int s2 = 0; s2 < 2; ++s2)
    async16(lds + 32768 + s2 * 8192 + dT, bS + (size_t)s2 * 64 * KS);
#pragma unroll
  for (int s2 = 0; s2 < 4; ++s2)
    async16(lds + 49152 + s2 * 8192 + dT, aS + (size_t)s2 * 64 * KS + BK);
#pragma unroll
  for (int s2 = 0; s2 < 2; ++s2)
    async16(lds + 49152 + 32768 + s2 * 8192 + dT, bS + (size_t)s2 * 64 * KS + BK);
  asm volatile("s_waitcnt vmcnt(6)" ::: "memory");  // tile0 landed, tile1 in flight
  __builtin_amdgcn_s_barrier();

  unsigned o0 = 0, o1 = 49152, o2 = 98304;  // tile T, T+1, T+2(staging)

  for (int T = 0; T < NT; ++T) {
    const bool pf = (T + 2) < NT;
    const int kpf = (T + 2) * BK;

    bf16x8 aF[4][2], bF[4][2];
    // ---- phase A: ds_read A i0-3 (both ks) + B j0-1; stage A slabs 0-2 of T+2
#pragma unroll
    for (int i = 0; i < 4; ++i) {
      aF[i][0] = *(const bf16x8*)(lds + o0 + aBase + i * 2048);
      aF[i][1] = *(const bf16x8*)(lds + o0 + ((aBase + i * 2048) ^ 64));
    }
#pragma unroll
    for (int j = 0; j < 2; ++j) {
      bF[j][0] = *(const bf16x8*)(lds + o0 + bBase + j * 2048);
      bF[j][1] = *(const bf16x8*)(lds + o0 + ((bBase + j * 2048) ^ 64));
    }
    if (pf) {
#pragma unroll
      for (int s2 = 0; s2 < 3; ++s2)
        async16(lds + o2 + s2 * 8192 + dT, aS + (size_t)s2 * 64 * KS + kpf);
    }
    __builtin_amdgcn_s_barrier();
    asm volatile("s_waitcnt lgkmcnt(0)" ::: "memory");
    __builtin_amdgcn_sched_barrier(0);
    __builtin_amdgcn_s_setprio(1);
#pragma unroll
    for (int ks = 0; ks < 2; ++ks)
#pragma unroll
      for (int i = 0; i < 4; ++i)
#pragma unroll
        for (int j = 0; j < 2; ++j)
          acc[i][j] = __builtin_amdgcn_mfma_f32_16x16x32_bf16(aF[i][ks], bF[j][ks], acc[i][j], 0, 0, 0);
    __builtin_amdgcn_s_setprio(0);
    __builtin_amdgcn_s_barrier();

    // ---- phase B: ds_read B j2-3; stage A slab3 + B slabs 0-1 of T+2
#pragma unroll
    for (int j = 2; j < 4; ++j) {
      bF[j][0] = *(const bf16x8*)(lds + o0 + bBase + j * 2048);
      bF[j][1] = *(const bf16x8*)(lds + o0 + ((bBase + j * 2048) ^ 64));
    }
    if (pf) {
      async16(lds + o2 + 3 * 8192 + dT, aS + (size_t)3 * 64 * KS + kpf);
#pragma unroll
      for (int s2 = 0; s2 < 2; ++s2)
        async16(lds + o2 + 32768 + s2 * 8192 + dT, bS + (size_t)s2 * 64 * KS + kpf);
      // wait tile T+1 (oldest 6); tile T+2's 6 loads stay in flight
      asm volatile("s_waitcnt vmcnt(6)" ::: "memory");
    } else {
      asm volatile("s_waitcnt vmcnt(0)" ::: "memory");  // tail: drain
    }
    __builtin_amdgcn_s_barrier();
    asm volatile("s_waitcnt lgkmcnt(0)" ::: "memory");
    __builtin_amdgcn_sched_barrier(0);
    __builtin_amdgcn_s_setprio(1);
#pragma unroll
    for (int ks = 0; ks < 2; ++ks)
#pragma unroll
      for (int i = 0; i < 4; ++i)
#pragma unroll
        for (int j = 2; j < 4; ++j)
          acc[i][j] = __builtin_amdgcn_mfma_f32_16x16x32_bf16(aF[i][ks], bF[j][ks], acc[i][j], 0, 0, 0);
    __builtin_amdgcn_s_setprio(0);
    __builtin_amdgcn_s_barrier();

    const unsigned tmp = o0; o0 = o1; o1 = o2; o2 = tmp;
  }

  // C/D layout: col = lane&15, row = (lane>>4)*4 + reg
  const int cm = wr * 64 + ((lane >> 4) << 2);
  const int cn = wc * 64 + (lane & 15);
  if (MODE == 0) {
#pragma unroll
    for (int i = 0; i < 4; ++i)
#pragma unroll
      for (int r = 0; r < 4; ++r) {
        const int m = m0 + cm + i * 16 + r;
        float rs = 0.f;
#pragma unroll
        for (int j = 0; j < 4; ++j) {
          const float e = __expf(fminf(acc[i][j][r] * 0.03125f, 30.0f));
          rs += e;
          Cb[(size_t)m * NS + n0 + cn + j * 16] = (__bf16)e;
        }
        rs += __shfl_xor(rs, 1, 64);
        rs += __shfl_xor(rs, 2, 64);
        rs += __shfl_xor(rs, 4, 64);
        rs += __shfl_xor(rs, 8, 64);
        if ((lane & 15) == 0) atomicAdd(&lsum[m], rs);
      }
  } else {
#pragma unroll
    for (int i = 0; i < 4; ++i)
#pragma unroll
      for (int r = 0; r < 4; ++r) {
        const int m = m0 + cm + i * 16 + r;
        const float inv = 1.0f / lsum[m];
#pragma unroll
        for (int j = 0; j < 4; ++j)
          Cf[(size_t)m * NS + n0 + cn + j * 16] = acc[i][j][r] * inv;
      }
  }
}

extern "C" void kernel_launch(void* const* d_in, const int* in_sizes, int n_in,
                              void* d_out, int out_size, void* d_ws, size_t ws_size,
                              hipStream_t stream) {
  const float* x = (const float*)d_in[0];  // [8192][1024] fp32
  const float* K = (const float*)d_in[1];  // [4096][1024] fp32
  const float* V = (const float*)d_in[2];  // [4096][1024] fp32
  float* out = (float*)d_out;              // [8192][1024] fp32

  char* ws = (char*)d_ws;
  __bf16* xb = (__bf16*)ws;                        // 16 MiB
  __bf16* Kb = (__bf16*)(ws + (16u << 20));        // 8 MiB
  __bf16* Vt = (__bf16*)(ws + (24u << 20));        // 8 MiB
  __bf16* P  = (__bf16*)(ws + (32u << 20));        // 64 MiB
  float*  l  = (float*)(ws + (96u << 20));         // 32 KiB

  preprocess_kernel<<<4097, 256, 0, stream>>>(x, K, V, xb, Kb, Vt, l);
  // P = exp(xb @ Kb^T / 32), fused row sums  (M=8192 N=4096 K=1024), 1024 blocks
  gemm_kernel<0, 1024, 4096><<<1024, 512, 0, stream>>>(xb, Kb, P, nullptr, l);
  // out = (P @ Vt-rows) / l  (M=8192 N=1024 K=4096), 256 blocks
  gemm_kernel<1, 4096, 1024><<<256, 512, 0, stream>>>(P, Vt, nullptr, out, l);
}